// Round 1
// baseline (235.131 us; speedup 1.0000x reference)
//
#include <hip/hip_runtime.h>
#include <hip/hip_bf16.h>

#define CHAR_EMB 30
#define NFILT    30
#define WLEN     40
#define TOUT     38      // WLEN - K + 1
#define OUTC     900     // CHAR_EMB * NFILT
#define WORD_EMB 100
#define ROWP     44      // padded LDS row stride (floats); 44*4=176 bytes, 16B aligned

__global__ __launch_bounds__(256) void encoder_kernel(
    const int*   __restrict__ char_ids,   // [BS, 40]
    const int*   __restrict__ word_ids,   // [BS]
    const float* __restrict__ char_emb,   // [102, 30]
    const float* __restrict__ conv_w,     // [900, 1, 3]
    const float* __restrict__ conv_b,     // [900]
    const float* __restrict__ glove,      // [400002, 100]
    float*       __restrict__ out,        // [BS, 1000]
    int BS)
{
    const int n   = blockIdx.x;
    const int tid = threadIdx.x;

    __shared__ float xs[CHAR_EMB * ROWP];  // x[c][t] at xs[c*ROWP + t]
    __shared__ int   cid[WLEN];

    if (tid < WLEN) cid[tid] = char_ids[n * WLEN + tid];
    __syncthreads();

    // gather char embeddings: 40 chars x 30 dims = 1200 floats
    for (int i = tid; i < WLEN * CHAR_EMB; i += 256) {
        const int t = i / CHAR_EMB;
        const int c = i - t * CHAR_EMB;
        xs[c * ROWP + t] = char_emb[cid[t] * CHAR_EMB + c];
    }
    __syncthreads();

    float* orow = out + (long)n * (OUTC + WORD_EMB);

    // depthwise conv + max-over-time: channel o uses input row g = o/30
    for (int o = tid; o < OUTC; o += 256) {
        const int g = o / NFILT;
        const float w0 = conv_w[o * 3 + 0];
        const float w1 = conv_w[o * 3 + 1];
        const float w2 = conv_w[o * 3 + 2];

        // load full 40-float row into registers via 10 x b128 LDS reads
        float xr[WLEN];
        const float4* rp = reinterpret_cast<const float4*>(&xs[g * ROWP]);
        #pragma unroll
        for (int k = 0; k < WLEN / 4; ++k) {
            float4 q = rp[k];
            xr[4 * k + 0] = q.x;
            xr[4 * k + 1] = q.y;
            xr[4 * k + 2] = q.z;
            xr[4 * k + 3] = q.w;
        }

        float m = -3.4e38f;
        #pragma unroll
        for (int t = 0; t < TOUT; ++t) {
            float v = fmaf(w0, xr[t], fmaf(w1, xr[t + 1], w2 * xr[t + 2]));
            m = fmaxf(m, v);
        }
        orow[o] = m + conv_b[o];
    }

    // glove word-embedding copy: 100 floats, coalesced
    if (tid < WORD_EMB) {
        const int wid = word_ids[n];
        orow[OUTC + tid] = glove[(long)wid * WORD_EMB + tid];
    }
}

extern "C" void kernel_launch(void* const* d_in, const int* in_sizes, int n_in,
                              void* d_out, int out_size, void* d_ws, size_t ws_size,
                              hipStream_t stream) {
    const int*   char_ids = (const int*)  d_in[0];
    const int*   word_ids = (const int*)  d_in[1];
    const float* char_emb = (const float*)d_in[2];
    const float* conv_w   = (const float*)d_in[3];
    const float* conv_b   = (const float*)d_in[4];
    const float* glove    = (const float*)d_in[5];
    float*       out      = (float*)      d_out;

    const int BS = in_sizes[1];  // 64*128 = 8192 words

    encoder_kernel<<<BS, 256, 0, stream>>>(
        char_ids, word_ids, char_emb, conv_w, conv_b, glove, out, BS);
}